// Round 5
// baseline (2164.363 us; speedup 1.0000x reference)
//
#include <hip/hip_runtime.h>
#include <stdint.h>

#define N_NODES 20000
#define E_EDGES 640000
#define IN_DIM  128
#define HID     256
#define MAXW    512
#define HEADS   32
#define BN_EPS  1e-5f

typedef __attribute__((ext_vector_type(8))) short bf16x8;
typedef __attribute__((ext_vector_type(4))) float f32x4;
typedef unsigned short ushort_t;

static __device__ __forceinline__ float bf2f(ushort_t u){
  union { unsigned int i; float f; } v; v.i = ((unsigned int)u) << 16; return v.f;
}
static __device__ __forceinline__ ushort_t f2bf(float f){
  union { float f; unsigned int i; } v; v.f = f;
  unsigned int r = v.i + 0x7fffu + ((v.i >> 16) & 1u);
  return (ushort_t)(r >> 16);
}

// ---------------- K0: init (zero G, s, deg) ----------------
__global__ void k_init(float* __restrict__ G, float* __restrict__ s,
                       int* __restrict__ deg){
  int i = blockIdx.x * blockDim.x + threadIdx.x;
  int stride = gridDim.x * blockDim.x;
  float4 z4 = make_float4(0.f, 0.f, 0.f, 0.f);
  float4* Gd = (float4*)G;
  for (int j = i; j < 256 * 256 / 4; j += stride) Gd[j] = z4;
  for (int j = i; j < N_NODES; j += stride) deg[j] = 0;
  if (i < 256) s[i] = 0.f;
}

// ---------------- K-detect: is edge_index stored as int64? ----------------
__global__ void k_detect(const int* __restrict__ ei, int* __restrict__ flag){
  __shared__ int any_nz;
  if (threadIdx.x == 0) any_nz = 0;
  __syncthreads();
  int nz = 0;
  for (int i = threadIdx.x; i < 4096; i += 256)
    if (ei[2 * i + 1] != 0) nz = 1;
  if (nz) atomicOr(&any_nz, 1);
  __syncthreads();
  if (threadIdx.x == 0) flag[0] = (any_nz == 0) ? 1 : 0;   // 1 => int64 layout
}

// ---------------- CSR build: histogram ----------------
__global__ __launch_bounds__(256) void k_hist(const int* __restrict__ ei,
                                              const int* __restrict__ flag,
                                              int* __restrict__ deg){
  int e = blockIdx.x * 256 + threadIdx.x;
  if (e >= E_EDGES) return;
  int src, dst;
  if (flag[0]){ src = ei[2 * e]; dst = ei[2 * E_EDGES + 2 * e]; }
  else        { src = ei[e];     dst = ei[E_EDGES + e]; }
  if ((unsigned)src >= N_NODES || (unsigned)dst >= N_NODES) return;
  atomicAdd(&deg[dst], 1);
}

// ---------------- CSR build: exclusive scan (1 block) ----------------
__global__ __launch_bounds__(256) void k_scan(const int* __restrict__ deg,
                                              int* __restrict__ start,
                                              int* __restrict__ cursor){
  __shared__ int tot[256], pre[256];
  int t = threadIdx.x;
  int i0 = t * 80;
  int cnt = i0 < N_NODES ? (N_NODES - i0 < 80 ? N_NODES - i0 : 80) : 0;
  int ssum = 0;
  for (int i = 0; i < cnt; i++) ssum += deg[i0 + i];
  tot[t] = ssum;
  __syncthreads();
  if (t == 0){ int r = 0; for (int i = 0; i < 256; i++){ pre[i] = r; r += tot[i]; } }
  __syncthreads();
  int base = pre[t];
  for (int i = 0; i < cnt; i++){
    start[i0 + i] = base; cursor[i0 + i] = base; base += deg[i0 + i];
  }
}

// ---------------- CSR build: scatter edge sources ----------------
__global__ __launch_bounds__(256) void k_scatter(const int* __restrict__ ei,
                                                 const int* __restrict__ flag,
                                                 int* __restrict__ cursor,
                                                 int* __restrict__ eids){
  int e = blockIdx.x * 256 + threadIdx.x;
  if (e >= E_EDGES) return;
  int src, dst;
  if (flag[0]){ src = ei[2 * e]; dst = ei[2 * E_EDGES + 2 * e]; }
  else        { src = ei[e];     dst = ei[E_EDGES + e]; }
  if ((unsigned)src >= N_NODES || (unsigned)dst >= N_NODES) return;
  int p = atomicAdd(&cursor[dst], 1);
  eids[p] = src;
}

// ---------------- K-agg: agg[dst] = x[dst] + sum_{e in bucket} x[src_e] ----------------
__global__ __launch_bounds__(256) void k_agg(const float* __restrict__ x,
                                             const int* __restrict__ start,
                                             const int* __restrict__ deg,
                                             const int* __restrict__ eids,
                                             float* __restrict__ agg){
  int wid = (blockIdx.x * 256 + threadIdx.x) >> 6;
  int lane = threadIdx.x & 63;
  if (wid >= N_NODES) return;
  int s0 = start[wid], d = deg[wid];
  float2 acc = *(const float2*)(x + (size_t)wid * IN_DIM + 2 * lane);
  int i = 0;
  for (; i + 4 <= d; i += 4){
    int e0 = eids[s0+i], e1 = eids[s0+i+1], e2 = eids[s0+i+2], e3 = eids[s0+i+3];
    float2 v0 = *(const float2*)(x + (size_t)e0 * IN_DIM + 2 * lane);
    float2 v1 = *(const float2*)(x + (size_t)e1 * IN_DIM + 2 * lane);
    float2 v2 = *(const float2*)(x + (size_t)e2 * IN_DIM + 2 * lane);
    float2 v3 = *(const float2*)(x + (size_t)e3 * IN_DIM + 2 * lane);
    acc.x += (v0.x + v1.x) + (v2.x + v3.x);
    acc.y += (v0.y + v1.y) + (v2.y + v3.y);
  }
  for (; i < d; i++){
    int e0 = eids[s0+i];
    float2 v0 = *(const float2*)(x + (size_t)e0 * IN_DIM + 2 * lane);
    acc.x += v0.x; acc.y += v0.y;
  }
  *(float2*)(agg + (size_t)wid * IN_DIM + 2 * lane) = acc;
}

// ---------------- K2: h = relu(agg @ Wb + bb) -> bf16; col-sums s ----------------
__global__ __launch_bounds__(256) void k_backbone(const float* __restrict__ agg,
                                                  const float* __restrict__ Wb,
                                                  const float* __restrict__ bb,
                                                  ushort_t* __restrict__ hbf,
                                                  float* __restrict__ s){
  __shared__ float WbS[32][256];
  __shared__ float aggS[32][36];
  int c = threadIdx.x;
  int n0 = blockIdx.x * 32;      // 625 blocks * 32 = 20000 exactly
  float acc[32];
  float bias = bb[c];
  #pragma unroll
  for (int i = 0; i < 32; i++) acc[i] = bias;
  for (int dc = 0; dc < 4; ++dc){
    __syncthreads();
    const float4* wsrc = (const float4*)(Wb + dc * 32 * 256);
    float4* wdst = (float4*)&WbS[0][0];
    #pragma unroll
    for (int i = 0; i < 8; i++) wdst[c + i * 256] = wsrc[c + i * 256];
    {
      int n = c >> 3, c4 = (c & 7) * 4;
      float4 v = *(const float4*)(agg + (size_t)(n0 + n) * IN_DIM + dc * 32 + c4);
      aggS[n][c4 + 0] = v.x; aggS[n][c4 + 1] = v.y;
      aggS[n][c4 + 2] = v.z; aggS[n][c4 + 3] = v.w;
    }
    __syncthreads();
    for (int d = 0; d < 32; ++d){
      float w = WbS[d][c];
      #pragma unroll
      for (int n = 0; n < 32; n++) acc[n] += aggS[n][d] * w;
    }
  }
  float ls = 0.f;
  #pragma unroll
  for (int n = 0; n < 32; n++){
    float hv = acc[n] > 0.f ? acc[n] : 0.f;
    ushort_t hb = f2bf(hv);
    hbf[(size_t)(n0 + n) * HID + c] = hb;
    ls += bf2f(hb);
  }
  unsafeAtomicAdd(&s[c], ls);
}

// ---------------- K3: Gram G = h^T h (f32, split-K with atomics) ----------------
__global__ __launch_bounds__(256) void k_gram(const ushort_t* __restrict__ hbf,
                                              float* __restrict__ G){
  __shared__ float sA[16][68], sB[16][68];
  int t = threadIdx.x, tx = t & 15, ty = t >> 4;
  int ta = blockIdx.x >> 2, tb = blockIdx.x & 3;
  int ca = ta * 64, cb = tb * 64;
  int nbase = blockIdx.y * 800;   // 25 * 800 = 20000 exactly
  float acc[4][4] = {};
  for (int nb = 0; nb < 800; nb += 16){
    __syncthreads();
    {
      int row = t >> 4, c4 = (t & 15) * 4;
      const ushort_t* p = hbf + (size_t)(nbase + nb + row) * HID;
      ushort4 va = *(const ushort4*)(p + ca + c4);
      ushort4 vb = *(const ushort4*)(p + cb + c4);
      sA[row][c4+0]=bf2f(va.x); sA[row][c4+1]=bf2f(va.y); sA[row][c4+2]=bf2f(va.z); sA[row][c4+3]=bf2f(va.w);
      sB[row][c4+0]=bf2f(vb.x); sB[row][c4+1]=bf2f(vb.y); sB[row][c4+2]=bf2f(vb.z); sB[row][c4+3]=bf2f(vb.w);
    }
    __syncthreads();
    #pragma unroll
    for (int i = 0; i < 16; i++){
      float a0=sA[i][ty*4+0], a1=sA[i][ty*4+1], a2=sA[i][ty*4+2], a3=sA[i][ty*4+3];
      float b0=sB[i][tx*4+0], b1=sB[i][tx*4+1], b2=sB[i][tx*4+2], b3=sB[i][tx*4+3];
      acc[0][0]+=a0*b0; acc[0][1]+=a0*b1; acc[0][2]+=a0*b2; acc[0][3]+=a0*b3;
      acc[1][0]+=a1*b0; acc[1][1]+=a1*b1; acc[1][2]+=a1*b2; acc[1][3]+=a1*b3;
      acc[2][0]+=a2*b0; acc[2][1]+=a2*b1; acc[2][2]+=a2*b2; acc[2][3]+=a2*b3;
      acc[3][0]+=a3*b0; acc[3][1]+=a3*b1; acc[3][2]+=a3*b2; acc[3][3]+=a3*b3;
    }
  }
  #pragma unroll
  for (int p = 0; p < 4; p++)
    #pragma unroll
    for (int q = 0; q < 4; q++)
      unsafeAtomicAdd(&G[(size_t)(ca + ty*4 + p) * 256 + cb + tx*4 + q], acc[p][q]);
}

// ---------------- K5: transpose+convert W1->W1T, W2->W2T (bf16) ----------------
__global__ __launch_bounds__(256) void k_transpose(const float* __restrict__ W1,
                                                   const float* __restrict__ W2,
                                                   ushort_t* __restrict__ w1t,
                                                   ushort_t* __restrict__ w2t){
  __shared__ float tile[32][33];
  int which = blockIdx.z, h = blockIdx.y, b = blockIdx.x;
  const float* src; ushort_t* dst; int R, C;
  if (which == 0){ src = W1 + (size_t)h * 256 * 512; dst = w1t + (size_t)h * 512 * 256; R = 256; C = 512; }
  else           { src = W2 + (size_t)h * 512 * 256; dst = w2t + (size_t)h * 256 * 512; R = 512; C = 256; }
  int tcn = C >> 5;
  int tr = b / tcn, tc = b % tcn;
  int r0 = tr * 32, c0 = tc * 32;
  int tx = threadIdx.x & 31, ty = threadIdx.x >> 5;
  #pragma unroll
  for (int i = 0; i < 32; i += 8) tile[ty + i][tx] = src[(size_t)(r0 + ty + i) * C + c0 + tx];
  __syncthreads();
  #pragma unroll
  for (int i = 0; i < 32; i += 8) dst[(size_t)(c0 + ty + i) * R + r0 + tx] = f2bf(tile[tx][ty + i]);
}

// ---------------- K4: BN stats -> fold to a = relu(z*A + B) ----------------
__global__ __launch_bounds__(256) void k_stats(const float* __restrict__ G,
                                               const float* __restrict__ s,
                                               const ushort_t* __restrict__ w1t,
                                               const float* __restrict__ b1,
                                               const float* __restrict__ gamma,
                                               const float* __restrict__ beta,
                                               float* __restrict__ As,
                                               float* __restrict__ Bs){
  __shared__ ushort_t wL[256][64];
  __shared__ float GL[16][256];
  __shared__ float sL[256];
  __shared__ float red[4][64];
  int h = blockIdx.y, m0 = blockIdx.x * 64;
  int t = threadIdx.x, m = t & 63, q = t >> 6;
  {
    int mm = t >> 2, part = t & 3;
    const ushort_t* src = w1t + ((size_t)h * 512 + m0 + mm) * 256 + part * 64;
    #pragma unroll
    for (int k4 = 0; k4 < 16; ++k4){
      ushort4 v = *(const ushort4*)(src + k4 * 4);
      int kb = part * 64 + k4 * 4;
      wL[kb+0][mm]=v.x; wL[kb+1][mm]=v.y; wL[kb+2][mm]=v.z; wL[kb+3][mm]=v.w;
    }
  }
  sL[t & 255] = s[t & 255];
  float quad = 0.f;
  for (int dc = 0; dc < 16; ++dc){
    __syncthreads();
    const float4* gs = (const float4*)(G + (size_t)dc * 16 * 256);
    float4* gd = (float4*)&GL[0][0];
    #pragma unroll
    for (int i = 0; i < 4; i++) gd[t + i * 256] = gs[t + i * 256];
    __syncthreads();
    #pragma unroll
    for (int i = 0; i < 4; i++){
      int dl = q * 4 + i;
      float wd = bf2f(wL[dc * 16 + dl][m]);
      float u = 0.f;
      for (int k = 0; k < 256; ++k) u += GL[dl][k] * bf2f(wL[k][m]);
      quad += wd * u;
    }
  }
  red[q][m] = quad;
  __syncthreads();
  if (q == 0){
    float qd = red[0][m] + red[1][m] + red[2][m] + red[3][m];
    float dot_s = 0.f;
    for (int k = 0; k < 256; ++k) dot_s += sL[k] * bf2f(wL[k][m]);
    float b1v = b1[(size_t)h * 512 + m0 + m];
    float invN = 1.f / (float)N_NODES;
    float mean = dot_s * invN + b1v;
    float ez2 = (qd + 2.f * b1v * dot_s) * invN + b1v * b1v;
    float var = ez2 - mean * mean;
    float rstd = rsqrtf(var + BN_EPS);
    float gv = gamma[(size_t)h * 512 + m0 + m];
    float be = beta[(size_t)h * 512 + m0 + m];
    float Av = rstd * gv;
    As[(size_t)h * 512 + m0 + m] = Av;
    Bs[(size_t)h * 512 + m0 + m] = be - mean * Av;
  }
}

// ---------------- K6 v3: fused GEMM1->BN/ReLU->GEMM2, NO LDS, NO barriers ----------------
// 256 threads = 4 independent waves; each wave owns 32 nodes (2 sets of 16).
// Weight fragments read directly from global (identical addrs across waves -> L1).
// GEMM1 output redistributed to GEMM2 A-operand layout via ds_bpermute (in-register).
__global__ __launch_bounds__(256, 2) void k_main(const ushort_t* __restrict__ hbf,
                                                 const ushort_t* __restrict__ w1t,
                                                 const ushort_t* __restrict__ w2t,
                                                 const float* __restrict__ As,
                                                 const float* __restrict__ Bs,
                                                 const float* __restrict__ b2,
                                                 float* __restrict__ out){
  const int h = blockIdx.y;
  const int t = threadIdx.x;
  const int w = t >> 6, l = t & 63;
  const int l15 = l & 15, l4 = l >> 4;
  const int nw = blockIdx.x * 128 + w * 32;   // wave's node base
  const f32x4 fzero = {0.f, 0.f, 0.f, 0.f};
  const bf16x8 bzero = {0,0,0,0,0,0,0,0};

  // persistent h fragments: 2 nsets x 8 k-octets
  bf16x8 afr[2][8];
  #pragma unroll
  for (int nset = 0; nset < 2; nset++){
    int row = nw + nset * 16 + l15;
    const ushort_t* p = hbf + (size_t)row * HID + l4 * 8;
    #pragma unroll
    for (int kk = 0; kk < 8; kk++){
      bf16x8 v = bzero;
      if (row < N_NODES) v = *(const bf16x8*)(p + kk * 32);
      afr[nset][kk] = v;
    }
  }
  f32x4 oacc[16][2];   // [dd-tile][nset]
  #pragma unroll
  for (int i = 0; i < 16; i++){ oacc[i][0] = fzero; oacc[i][1] = fzero; }

  const float* Asp = As + (size_t)h * 512;
  const float* Bsp = Bs + (size_t)h * 512;
  const ushort_t* w1g = w1t + (size_t)h * 512 * 256;
  const ushort_t* w2g = w2t + (size_t)h * 256 * 512;

  const int addrA = (((((l4 & 1) << 1) << 4) | l15) << 2);   // byte index: producer lane *4
  const int addrB = addrA + 64;                              // +16 lanes
  const bool ct1 = (l4 >> 1) != 0;

  for (int c = 0; c < 16; ++c){
    const int mc0 = c * 32;
    // ---- GEMM1 (swapped): zt = w1 * h^T; lane holds m = ct*16+l4*4+r, n = nset*16+l15
    f32x4 zt[2][2];
    zt[0][0] = fzero; zt[0][1] = fzero; zt[1][0] = fzero; zt[1][1] = fzero;
    #pragma unroll
    for (int kk = 0; kk < 8; kk++){
      #pragma unroll
      for (int ct = 0; ct < 2; ct++){
        bf16x8 wf = *(const bf16x8*)(w1g + (size_t)(mc0 + ct * 16 + l15) * 256 + kk * 32 + l4 * 8);
        zt[0][ct] = __builtin_amdgcn_mfma_f32_16x16x32_bf16(wf, afr[0][kk], zt[0][ct], 0, 0, 0);
        zt[1][ct] = __builtin_amdgcn_mfma_f32_16x16x32_bf16(wf, afr[1][kk], zt[1][ct], 0, 0, 0);
      }
    }
    // ---- BN fold + ReLU + pack to bf16 pairs
    unsigned plo[2][2], phi[2][2];   // [nset][ct]
    #pragma unroll
    for (int ct = 0; ct < 2; ct++){
      int mb = mc0 + ct * 16 + l4 * 4;
      float4 Av = *(const float4*)(Asp + mb);
      float4 Bv = *(const float4*)(Bsp + mb);
      #pragma unroll
      for (int nset = 0; nset < 2; nset++){
        float a0 = zt[nset][ct][0] * Av.x + Bv.x; a0 = a0 > 0.f ? a0 : 0.f;
        float a1 = zt[nset][ct][1] * Av.y + Bv.y; a1 = a1 > 0.f ? a1 : 0.f;
        float a2 = zt[nset][ct][2] * Av.z + Bv.z; a2 = a2 > 0.f ? a2 : 0.f;
        float a3 = zt[nset][ct][3] * Av.w + Bv.w; a3 = a3 > 0.f ? a3 : 0.f;
        plo[nset][ct] = (unsigned)f2bf(a0) | ((unsigned)f2bf(a1) << 16);
        phi[nset][ct] = (unsigned)f2bf(a2) | ((unsigned)f2bf(a3) << 16);
      }
    }
    // ---- redistribute to GEMM2 A-layout: aa[nset] = a[n = nset*16+l15][m-octet l4]
    bf16x8 aa[2];
    #pragma unroll
    for (int nset = 0; nset < 2; nset++){
      int q0a = __builtin_amdgcn_ds_bpermute(addrA, (int)plo[nset][0]);
      int q0b = __builtin_amdgcn_ds_bpermute(addrA, (int)plo[nset][1]);
      int q1a = __builtin_amdgcn_ds_bpermute(addrA, (int)phi[nset][0]);
      int q1b = __builtin_amdgcn_ds_bpermute(addrA, (int)phi[nset][1]);
      int q2a = __builtin_amdgcn_ds_bpermute(addrB, (int)plo[nset][0]);
      int q2b = __builtin_amdgcn_ds_bpermute(addrB, (int)plo[nset][1]);
      int q3a = __builtin_amdgcn_ds_bpermute(addrB, (int)phi[nset][0]);
      int q3b = __builtin_amdgcn_ds_bpermute(addrB, (int)phi[nset][1]);
      uint4 q;
      q.x = (unsigned)(ct1 ? q0b : q0a);
      q.y = (unsigned)(ct1 ? q1b : q1a);
      q.z = (unsigned)(ct1 ? q2b : q2a);
      q.w = (unsigned)(ct1 ? q3b : q3a);
      aa[nset] = *(bf16x8*)&q;
    }
    // ---- GEMM2 (swapped): oacc[ddt][nset] += w2[dd][m] * aa
    #pragma unroll
    for (int ddt = 0; ddt < 16; ddt++){
      bf16x8 wf2 = *(const bf16x8*)(w2g + (size_t)(ddt * 16 + l15) * 512 + mc0 + l4 * 8);
      oacc[ddt][0] = __builtin_amdgcn_mfma_f32_16x16x32_bf16(wf2, aa[0], oacc[ddt][0], 0, 0, 0);
      oacc[ddt][1] = __builtin_amdgcn_mfma_f32_16x16x32_bf16(wf2, aa[1], oacc[ddt][1], 0, 0, 0);
    }
  }
  // ---- epilogue: out[n][h][dd..dd+3] float4 (dd = ddt*16 + l4*4 + r, n = nw + nset*16 + l15)
  #pragma unroll
  for (int ddt = 0; ddt < 16; ddt++){
    int dd = ddt * 16 + l4 * 4;
    float4 b2v = *(const float4*)(b2 + (size_t)h * 256 + dd);
    #pragma unroll
    for (int nset = 0; nset < 2; nset++){
      int n = nw + nset * 16 + l15;
      if (n < N_NODES){
        float4 v;
        v.x = oacc[ddt][nset][0] + b2v.x;
        v.y = oacc[ddt][nset][1] + b2v.y;
        v.z = oacc[ddt][nset][2] + b2v.z;
        v.w = oacc[ddt][nset][3] + b2v.w;
        *(float4*)(out + (size_t)n * (HEADS * HID) + h * HID + dd) = v;
      }
    }
  }
}

extern "C" void kernel_launch(void* const* d_in, const int* in_sizes, int n_in,
                              void* d_out, int out_size, void* d_ws, size_t ws_size,
                              hipStream_t stream){
  const float* x     = (const float*)d_in[0];
  const int*   ei    = (const int*)  d_in[1];
  const float* Wb    = (const float*)d_in[2];
  const float* bb    = (const float*)d_in[3];
  const float* W1    = (const float*)d_in[4];
  const float* b1    = (const float*)d_in[5];
  const float* gamma = (const float*)d_in[6];
  const float* beta  = (const float*)d_in[7];
  const float* W2    = (const float*)d_in[8];
  const float* b2    = (const float*)d_in[9];
  float* out = (float*)d_out;

  char* ws = (char*)d_ws;
  size_t off = 0;
  auto alloc = [&](size_t bytes){ void* p = ws + off; off += (bytes + 255) & ~(size_t)255; return p; };
  float*    agg  = (float*)   alloc((size_t)N_NODES * IN_DIM * 4);
  ushort_t* hbf  = (ushort_t*)alloc((size_t)N_NODES * HID * 2);
  ushort_t* w1t  = (ushort_t*)alloc((size_t)HEADS * MAXW * HID * 2);
  ushort_t* w2t  = (ushort_t*)alloc((size_t)HEADS * HID * MAXW * 2);
  float*    G    = (float*)   alloc(256 * 256 * 4);
  float*    s    = (float*)   alloc(256 * 4);
  float*    As   = (float*)   alloc((size_t)HEADS * MAXW * 4);
  float*    Bs   = (float*)   alloc((size_t)HEADS * MAXW * 4);
  int*      flg  = (int*)     alloc(256);
  int*      deg  = (int*)     alloc((size_t)N_NODES * 4);
  int*      st   = (int*)     alloc((size_t)N_NODES * 4);
  int*      cur  = (int*)     alloc((size_t)N_NODES * 4);
  int*      eids = (int*)     alloc((size_t)E_EDGES * 4);

  hipLaunchKernelGGL(k_init,      dim3(512),         dim3(256), 0, stream, G, s, deg);
  hipLaunchKernelGGL(k_detect,    dim3(1),           dim3(256), 0, stream, ei, flg);
  hipLaunchKernelGGL(k_transpose, dim3(128, 32, 2),  dim3(256), 0, stream, W1, W2, w1t, w2t);
  hipLaunchKernelGGL(k_hist,      dim3(2500),        dim3(256), 0, stream, ei, flg, deg);
  hipLaunchKernelGGL(k_scan,      dim3(1),           dim3(256), 0, stream, deg, st, cur);
  hipLaunchKernelGGL(k_scatter,   dim3(2500),        dim3(256), 0, stream, ei, flg, cur, eids);
  hipLaunchKernelGGL(k_agg,       dim3(5000),        dim3(256), 0, stream, x, st, deg, eids, agg);
  hipLaunchKernelGGL(k_backbone,  dim3(625),         dim3(256), 0, stream, agg, Wb, bb, hbf, s);
  hipLaunchKernelGGL(k_gram,      dim3(16, 25),      dim3(256), 0, stream, hbf, G);
  hipLaunchKernelGGL(k_stats,     dim3(8, 32),       dim3(256), 0, stream, G, s, w1t, b1, gamma, beta, As, Bs);
  hipLaunchKernelGGL(k_main,      dim3(157, 32),     dim3(256), 0, stream, hbf, w1t, w2t, As, Bs, b2, out);
}

// Round 6
// 1072.387 us; speedup vs baseline: 2.0183x; 2.0183x over previous
//
#include <hip/hip_runtime.h>
#include <stdint.h>

#define N_NODES 20000
#define E_EDGES 640000
#define IN_DIM  128
#define HID     256
#define MAXW    512
#define HEADS   32
#define BN_EPS  1e-5f

typedef __attribute__((ext_vector_type(8))) short bf16x8;
typedef __attribute__((ext_vector_type(4))) float f32x4;
typedef unsigned short ushort_t;

static __device__ __forceinline__ float bf2f(ushort_t u){
  union { unsigned int i; float f; } v; v.i = ((unsigned int)u) << 16; return v.f;
}
static __device__ __forceinline__ ushort_t f2bf(float f){
  union { float f; unsigned int i; } v; v.f = f;
  unsigned int r = v.i + 0x7fffu + ((v.i >> 16) & 1u);
  return (ushort_t)(r >> 16);
}

// ---------------- K0: init (zero G, s, deg) ----------------
__global__ void k_init(float* __restrict__ G, float* __restrict__ s,
                       int* __restrict__ deg){
  int i = blockIdx.x * blockDim.x + threadIdx.x;
  int stride = gridDim.x * blockDim.x;
  float4 z4 = make_float4(0.f, 0.f, 0.f, 0.f);
  float4* Gd = (float4*)G;
  for (int j = i; j < 256 * 256 / 4; j += stride) Gd[j] = z4;
  for (int j = i; j < N_NODES; j += stride) deg[j] = 0;
  if (i < 256) s[i] = 0.f;
}

// ---------------- K-detect: is edge_index stored as int64? ----------------
__global__ void k_detect(const int* __restrict__ ei, int* __restrict__ flag){
  __shared__ int any_nz;
  if (threadIdx.x == 0) any_nz = 0;
  __syncthreads();
  int nz = 0;
  for (int i = threadIdx.x; i < 4096; i += 256)
    if (ei[2 * i + 1] != 0) nz = 1;
  if (nz) atomicOr(&any_nz, 1);
  __syncthreads();
  if (threadIdx.x == 0) flag[0] = (any_nz == 0) ? 1 : 0;   // 1 => int64 layout
}

// ---------------- CSR build: histogram ----------------
__global__ __launch_bounds__(256) void k_hist(const int* __restrict__ ei,
                                              const int* __restrict__ flag,
                                              int* __restrict__ deg){
  int e = blockIdx.x * 256 + threadIdx.x;
  if (e >= E_EDGES) return;
  int src, dst;
  if (flag[0]){ src = ei[2 * e]; dst = ei[2 * E_EDGES + 2 * e]; }
  else        { src = ei[e];     dst = ei[E_EDGES + e]; }
  if ((unsigned)src >= N_NODES || (unsigned)dst >= N_NODES) return;
  atomicAdd(&deg[dst], 1);
}

// ---------------- CSR build: exclusive scan (1 block) ----------------
__global__ __launch_bounds__(256) void k_scan(const int* __restrict__ deg,
                                              int* __restrict__ start,
                                              int* __restrict__ cursor){
  __shared__ int tot[256], pre[256];
  int t = threadIdx.x;
  int i0 = t * 80;
  int cnt = i0 < N_NODES ? (N_NODES - i0 < 80 ? N_NODES - i0 : 80) : 0;
  int ssum = 0;
  for (int i = 0; i < cnt; i++) ssum += deg[i0 + i];
  tot[t] = ssum;
  __syncthreads();
  if (t == 0){ int r = 0; for (int i = 0; i < 256; i++){ pre[i] = r; r += tot[i]; } }
  __syncthreads();
  int base = pre[t];
  for (int i = 0; i < cnt; i++){
    start[i0 + i] = base; cursor[i0 + i] = base; base += deg[i0 + i];
  }
}

// ---------------- CSR build: scatter edge sources ----------------
__global__ __launch_bounds__(256) void k_scatter(const int* __restrict__ ei,
                                                 const int* __restrict__ flag,
                                                 int* __restrict__ cursor,
                                                 int* __restrict__ eids){
  int e = blockIdx.x * 256 + threadIdx.x;
  if (e >= E_EDGES) return;
  int src, dst;
  if (flag[0]){ src = ei[2 * e]; dst = ei[2 * E_EDGES + 2 * e]; }
  else        { src = ei[e];     dst = ei[E_EDGES + e]; }
  if ((unsigned)src >= N_NODES || (unsigned)dst >= N_NODES) return;
  int p = atomicAdd(&cursor[dst], 1);
  eids[p] = src;
}

// ---------------- K-agg: agg[dst] = x[dst] + sum_{e in bucket} x[src_e] ----------------
__global__ __launch_bounds__(256) void k_agg(const float* __restrict__ x,
                                             const int* __restrict__ start,
                                             const int* __restrict__ deg,
                                             const int* __restrict__ eids,
                                             float* __restrict__ agg){
  int wid = (blockIdx.x * 256 + threadIdx.x) >> 6;
  int lane = threadIdx.x & 63;
  if (wid >= N_NODES) return;
  int s0 = start[wid], d = deg[wid];
  float2 acc = *(const float2*)(x + (size_t)wid * IN_DIM + 2 * lane);
  int i = 0;
  for (; i + 4 <= d; i += 4){
    int e0 = eids[s0+i], e1 = eids[s0+i+1], e2 = eids[s0+i+2], e3 = eids[s0+i+3];
    float2 v0 = *(const float2*)(x + (size_t)e0 * IN_DIM + 2 * lane);
    float2 v1 = *(const float2*)(x + (size_t)e1 * IN_DIM + 2 * lane);
    float2 v2 = *(const float2*)(x + (size_t)e2 * IN_DIM + 2 * lane);
    float2 v3 = *(const float2*)(x + (size_t)e3 * IN_DIM + 2 * lane);
    acc.x += (v0.x + v1.x) + (v2.x + v3.x);
    acc.y += (v0.y + v1.y) + (v2.y + v3.y);
  }
  for (; i < d; i++){
    int e0 = eids[s0+i];
    float2 v0 = *(const float2*)(x + (size_t)e0 * IN_DIM + 2 * lane);
    acc.x += v0.x; acc.y += v0.y;
  }
  *(float2*)(agg + (size_t)wid * IN_DIM + 2 * lane) = acc;
}

// ---------------- K2: h = relu(agg @ Wb + bb) -> bf16; col-sums s ----------------
__global__ __launch_bounds__(256) void k_backbone(const float* __restrict__ agg,
                                                  const float* __restrict__ Wb,
                                                  const float* __restrict__ bb,
                                                  ushort_t* __restrict__ hbf,
                                                  float* __restrict__ s){
  __shared__ float WbS[32][256];
  __shared__ float aggS[32][36];
  int c = threadIdx.x;
  int n0 = blockIdx.x * 32;
  float acc[32];
  float bias = bb[c];
  #pragma unroll
  for (int i = 0; i < 32; i++) acc[i] = bias;
  for (int dc = 0; dc < 4; ++dc){
    __syncthreads();
    const float4* wsrc = (const float4*)(Wb + dc * 32 * 256);
    float4* wdst = (float4*)&WbS[0][0];
    #pragma unroll
    for (int i = 0; i < 8; i++) wdst[c + i * 256] = wsrc[c + i * 256];
    {
      int n = c >> 3, c4 = (c & 7) * 4;
      float4 v = *(const float4*)(agg + (size_t)(n0 + n) * IN_DIM + dc * 32 + c4);
      aggS[n][c4 + 0] = v.x; aggS[n][c4 + 1] = v.y;
      aggS[n][c4 + 2] = v.z; aggS[n][c4 + 3] = v.w;
    }
    __syncthreads();
    for (int d = 0; d < 32; ++d){
      float w = WbS[d][c];
      #pragma unroll
      for (int n = 0; n < 32; n++) acc[n] += aggS[n][d] * w;
    }
  }
  float ls = 0.f;
  #pragma unroll
  for (int n = 0; n < 32; n++){
    float hv = acc[n] > 0.f ? acc[n] : 0.f;
    ushort_t hb = f2bf(hv);
    hbf[(size_t)(n0 + n) * HID + c] = hb;
    ls += bf2f(hb);
  }
  unsafeAtomicAdd(&s[c], ls);
}

// ---------------- K3: Gram G = h^T h ----------------
__global__ __launch_bounds__(256) void k_gram(const ushort_t* __restrict__ hbf,
                                              float* __restrict__ G){
  __shared__ float sA[16][68], sB[16][68];
  int t = threadIdx.x, tx = t & 15, ty = t >> 4;
  int ta = blockIdx.x >> 2, tb = blockIdx.x & 3;
  int ca = ta * 64, cb = tb * 64;
  int nbase = blockIdx.y * 800;
  float acc[4][4] = {};
  for (int nb = 0; nb < 800; nb += 16){
    __syncthreads();
    {
      int row = t >> 4, c4 = (t & 15) * 4;
      const ushort_t* p = hbf + (size_t)(nbase + nb + row) * HID;
      ushort4 va = *(const ushort4*)(p + ca + c4);
      ushort4 vb = *(const ushort4*)(p + cb + c4);
      sA[row][c4+0]=bf2f(va.x); sA[row][c4+1]=bf2f(va.y); sA[row][c4+2]=bf2f(va.z); sA[row][c4+3]=bf2f(va.w);
      sB[row][c4+0]=bf2f(vb.x); sB[row][c4+1]=bf2f(vb.y); sB[row][c4+2]=bf2f(vb.z); sB[row][c4+3]=bf2f(vb.w);
    }
    __syncthreads();
    #pragma unroll
    for (int i = 0; i < 16; i++){
      float a0=sA[i][ty*4+0], a1=sA[i][ty*4+1], a2=sA[i][ty*4+2], a3=sA[i][ty*4+3];
      float b0=sB[i][tx*4+0], b1=sB[i][tx*4+1], b2=sB[i][tx*4+2], b3=sB[i][tx*4+3];
      acc[0][0]+=a0*b0; acc[0][1]+=a0*b1; acc[0][2]+=a0*b2; acc[0][3]+=a0*b3;
      acc[1][0]+=a1*b0; acc[1][1]+=a1*b1; acc[1][2]+=a1*b2; acc[1][3]+=a1*b3;
      acc[2][0]+=a2*b0; acc[2][1]+=a2*b1; acc[2][2]+=a2*b2; acc[2][3]+=a2*b3;
      acc[3][0]+=a3*b0; acc[3][1]+=a3*b1; acc[3][2]+=a3*b2; acc[3][3]+=a3*b3;
    }
  }
  #pragma unroll
  for (int p = 0; p < 4; p++)
    #pragma unroll
    for (int q = 0; q < 4; q++)
      unsafeAtomicAdd(&G[(size_t)(ca + ty*4 + p) * 256 + cb + tx*4 + q], acc[p][q]);
}

// ---------------- K5: transpose+convert W1->W1T, W2->W2T (bf16) ----------------
__global__ __launch_bounds__(256) void k_transpose(const float* __restrict__ W1,
                                                   const float* __restrict__ W2,
                                                   ushort_t* __restrict__ w1t,
                                                   ushort_t* __restrict__ w2t){
  __shared__ float tile[32][33];
  int which = blockIdx.z, h = blockIdx.y, b = blockIdx.x;
  const float* src; ushort_t* dst; int R, C;
  if (which == 0){ src = W1 + (size_t)h * 256 * 512; dst = w1t + (size_t)h * 512 * 256; R = 256; C = 512; }
  else           { src = W2 + (size_t)h * 512 * 256; dst = w2t + (size_t)h * 256 * 512; R = 512; C = 256; }
  int tcn = C >> 5;
  int tr = b / tcn, tc = b % tcn;
  int r0 = tr * 32, c0 = tc * 32;
  int tx = threadIdx.x & 31, ty = threadIdx.x >> 5;
  #pragma unroll
  for (int i = 0; i < 32; i += 8) tile[ty + i][tx] = src[(size_t)(r0 + ty + i) * C + c0 + tx];
  __syncthreads();
  #pragma unroll
  for (int i = 0; i < 32; i += 8) dst[(size_t)(c0 + ty + i) * R + r0 + tx] = f2bf(tile[tx][ty + i]);
}

// ---------------- K4: BN stats -> fold to a = relu(z*A + B) ----------------
__global__ __launch_bounds__(256) void k_stats(const float* __restrict__ G,
                                               const float* __restrict__ s,
                                               const ushort_t* __restrict__ w1t,
                                               const float* __restrict__ b1,
                                               const float* __restrict__ gamma,
                                               const float* __restrict__ beta,
                                               float* __restrict__ As,
                                               float* __restrict__ Bs){
  __shared__ ushort_t wL[256][64];
  __shared__ float GL[16][256];
  __shared__ float sL[256];
  __shared__ float red[4][64];
  int h = blockIdx.y, m0 = blockIdx.x * 64;
  int t = threadIdx.x, m = t & 63, q = t >> 6;
  {
    int mm = t >> 2, part = t & 3;
    const ushort_t* src = w1t + ((size_t)h * 512 + m0 + mm) * 256 + part * 64;
    #pragma unroll
    for (int k4 = 0; k4 < 16; ++k4){
      ushort4 v = *(const ushort4*)(src + k4 * 4);
      int kb = part * 64 + k4 * 4;
      wL[kb+0][mm]=v.x; wL[kb+1][mm]=v.y; wL[kb+2][mm]=v.z; wL[kb+3][mm]=v.w;
    }
  }
  sL[t & 255] = s[t & 255];
  float quad = 0.f;
  for (int dc = 0; dc < 16; ++dc){
    __syncthreads();
    const float4* gs = (const float4*)(G + (size_t)dc * 16 * 256);
    float4* gd = (float4*)&GL[0][0];
    #pragma unroll
    for (int i = 0; i < 4; i++) gd[t + i * 256] = gs[t + i * 256];
    __syncthreads();
    #pragma unroll
    for (int i = 0; i < 4; i++){
      int dl = q * 4 + i;
      float wd = bf2f(wL[dc * 16 + dl][m]);
      float u = 0.f;
      for (int k = 0; k < 256; ++k) u += GL[dl][k] * bf2f(wL[k][m]);
      quad += wd * u;
    }
  }
  red[q][m] = quad;
  __syncthreads();
  if (q == 0){
    float qd = red[0][m] + red[1][m] + red[2][m] + red[3][m];
    float dot_s = 0.f;
    for (int k = 0; k < 256; ++k) dot_s += sL[k] * bf2f(wL[k][m]);
    float b1v = b1[(size_t)h * 512 + m0 + m];
    float invN = 1.f / (float)N_NODES;
    float mean = dot_s * invN + b1v;
    float ez2 = (qd + 2.f * b1v * dot_s) * invN + b1v * b1v;
    float var = ez2 - mean * mean;
    float rstd = rsqrtf(var + BN_EPS);
    float gv = gamma[(size_t)h * 512 + m0 + m];
    float be = beta[(size_t)h * 512 + m0 + m];
    float Av = rstd * gv;
    As[(size_t)h * 512 + m0 + m] = Av;
    Bs[(size_t)h * 512 + m0 + m] = be - mean * Av;
  }
}

// ---------------- K6 v6: LDS weights (dbuf) + bpermute handoff, 1 barrier/chunk ----------------
// 8 waves (512 thr), 256 nodes/block; each wave owns 32 nodes, computes all 256 dd.
__global__ __launch_bounds__(512, 2) void k_main(const ushort_t* __restrict__ hbf,
                                                 const ushort_t* __restrict__ w1t,
                                                 const ushort_t* __restrict__ w2t,
                                                 const float* __restrict__ As,
                                                 const float* __restrict__ Bs,
                                                 const float* __restrict__ b2,
                                                 float* __restrict__ out){
  __shared__ __align__(16) char lds_all[65536];   // [0,32K): w1 dbuf; [32K,64K): w2 dbuf; reused as epilogue scratch
  const int h = blockIdx.y;
  const int n0 = blockIdx.x * 256;
  const int t = threadIdx.x;
  const int w = t >> 6, l = t & 63;
  const int l15 = l & 15, l4 = l >> 4;
  const int nw = n0 + w * 32;
  const f32x4 fzero = {0.f, 0.f, 0.f, 0.f};
  const bf16x8 bzero = {0,0,0,0,0,0,0,0};

  // persistent h fragments (B-operand): node col = l15, k-octet = l4
  bf16x8 afr[2][8];
  #pragma unroll
  for (int nset = 0; nset < 2; nset++){
    int row = nw + nset * 16 + l15;
    const ushort_t* p = hbf + (size_t)row * HID + l4 * 8;
    #pragma unroll
    for (int kk = 0; kk < 8; kk++){
      bf16x8 v = bzero;
      if (row < N_NODES) v = *(const bf16x8*)(p + kk * 32);
      afr[nset][kk] = v;
    }
  }
  f32x4 oacc[16][2];
  #pragma unroll
  for (int i = 0; i < 16; i++){ oacc[i][0] = fzero; oacc[i][1] = fzero; }

  const float* Asp = As + (size_t)h * 512;
  const float* Bsp = Bs + (size_t)h * 512;
  const ushort_t* w1g = w1t + (size_t)h * 512 * 256;
  const ushort_t* w2g = w2t + (size_t)h * 256 * 512;

  // staging geometry (granule = 16B): w1 chunk = 32 rows x 32 granules; w2 = 256 rows x 4 granules
  const int m_a0 = t >> 5,        g_a0 = t & 31;
  const int m_a1 = (t + 512) >> 5, g_a1 = (t + 512) & 31;
  const int dA0 = m_a0 * 512 + ((g_a0 ^ (m_a0 & 7)) * 16);
  const int dA1 = m_a1 * 512 + ((g_a1 ^ (m_a1 & 7)) * 16);
  const int d_b0 = t >> 2,        g_b0 = t & 3;
  const int d_b1 = (t + 512) >> 2, g_b1 = (t + 512) & 3;
  const int dB0 = d_b0 * 64 + ((g_b0 ^ (d_b0 & 3) ^ ((d_b0 >> 2) & 3)) * 16);
  const int dB1 = d_b1 * 64 + ((g_b1 ^ (d_b1 & 3) ^ ((d_b1 >> 2) & 3)) * 16);

  // prologue: stage chunk 0 -> buffer 0
  {
    uint4 a0 = *(const uint4*)(w1g + (size_t)m_a0 * 256 + g_a0 * 8);
    uint4 a1 = *(const uint4*)(w1g + (size_t)m_a1 * 256 + g_a1 * 8);
    uint4 b0 = *(const uint4*)(w2g + (size_t)d_b0 * 512 + g_b0 * 8);
    uint4 b1 = *(const uint4*)(w2g + (size_t)d_b1 * 512 + g_b1 * 8);
    *(uint4*)(lds_all + dA0) = a0;
    *(uint4*)(lds_all + dA1) = a1;
    *(uint4*)(lds_all + 32768 + dB0) = b0;
    *(uint4*)(lds_all + 32768 + dB1) = b1;
  }
  __syncthreads();

  const int addrA = ((((l4 & 1) << 1) << 4) | l15) << 2;   // producer lane * 4
  const int addrB = addrA + 64;
  const bool ct1 = (l4 >> 1) != 0;

  for (int c = 0; c < 16; ++c){
    const int cur = c & 1;
    const int mc0 = c * 32;
    const bool pf = (c < 15);
    uint4 va0, va1, vb0, vb1;
    if (pf){
      const int mn = mc0 + 32;
      va0 = *(const uint4*)(w1g + (size_t)(mn + m_a0) * 256 + g_a0 * 8);
      va1 = *(const uint4*)(w1g + (size_t)(mn + m_a1) * 256 + g_a1 * 8);
      vb0 = *(const uint4*)(w2g + (size_t)d_b0 * 512 + mn + g_b0 * 8);
      vb1 = *(const uint4*)(w2g + (size_t)d_b1 * 512 + mn + g_b1 * 8);
    }
    const char* w1b = lds_all + cur * 16384;
    const char* w2b = lds_all + 32768 + cur * 16384;

    // ---- GEMM1 (swapped): zt[nset][ct], C row = m-local (l4*4+r), col = node (l15)
    f32x4 zt[2][2];
    zt[0][0] = fzero; zt[0][1] = fzero; zt[1][0] = fzero; zt[1][1] = fzero;
    __builtin_amdgcn_s_setprio(1);
    #pragma unroll
    for (int kk = 0; kk < 8; kk++){
      #pragma unroll
      for (int ct = 0; ct < 2; ct++){
        int r1 = ct * 16 + l15;
        int gr = kk * 4 + l4;
        bf16x8 wf = *(const bf16x8*)(w1b + r1 * 512 + ((gr ^ (r1 & 7)) * 16));
        zt[0][ct] = __builtin_amdgcn_mfma_f32_16x16x32_bf16(wf, afr[0][kk], zt[0][ct], 0, 0, 0);
        zt[1][ct] = __builtin_amdgcn_mfma_f32_16x16x32_bf16(wf, afr[1][kk], zt[1][ct], 0, 0, 0);
      }
    }
    __builtin_amdgcn_s_setprio(0);

    // ---- BN fold + ReLU + pack
    unsigned plo[2][2], phi[2][2];   // [nset][ct]
    #pragma unroll
    for (int ct = 0; ct < 2; ct++){
      int mb = mc0 + ct * 16 + l4 * 4;
      float4 Av = *(const float4*)(Asp + mb);
      float4 Bv = *(const float4*)(Bsp + mb);
      #pragma unroll
      for (int nset = 0; nset < 2; nset++){
        float a0 = zt[nset][ct][0] * Av.x + Bv.x; a0 = a0 > 0.f ? a0 : 0.f;
        float a1 = zt[nset][ct][1] * Av.y + Bv.y; a1 = a1 > 0.f ? a1 : 0.f;
        float a2 = zt[nset][ct][2] * Av.z + Bv.z; a2 = a2 > 0.f ? a2 : 0.f;
        float a3 = zt[nset][ct][3] * Av.w + Bv.w; a3 = a3 > 0.f ? a3 : 0.f;
        plo[nset][ct] = (unsigned)f2bf(a0) | ((unsigned)f2bf(a1) << 16);
        phi[nset][ct] = (unsigned)f2bf(a2) | ((unsigned)f2bf(a3) << 16);
      }
    }
    // ---- redistribute (verified v5 layout): aa[nset] = a[node l15][m-octet l4]
    bf16x8 aa[2];
    #pragma unroll
    for (int nset = 0; nset < 2; nset++){
      int q0a = __builtin_amdgcn_ds_bpermute(addrA, (int)plo[nset][0]);
      int q0b = __builtin_amdgcn_ds_bpermute(addrA, (int)plo[nset][1]);
      int q1a = __builtin_amdgcn_ds_bpermute(addrA, (int)phi[nset][0]);
      int q1b = __builtin_amdgcn_ds_bpermute(addrA, (int)phi[nset][1]);
      int q2a = __builtin_amdgcn_ds_bpermute(addrB, (int)plo[nset][0]);
      int q2b = __builtin_amdgcn_ds_bpermute(addrB, (int)plo[nset][1]);
      int q3a = __builtin_amdgcn_ds_bpermute(addrB, (int)phi[nset][0]);
      int q3b = __builtin_amdgcn_ds_bpermute(addrB, (int)phi[nset][1]);
      uint4 q;
      q.x = (unsigned)(ct1 ? q0b : q0a);
      q.y = (unsigned)(ct1 ? q1b : q1a);
      q.z = (unsigned)(ct1 ? q2b : q2a);
      q.w = (unsigned)(ct1 ? q3b : q3a);
      aa[nset] = *(bf16x8*)&q;
    }
    // ---- GEMM2 (swapped): A = w2 rows dd (l15), B = aa
    __builtin_amdgcn_s_setprio(1);
    #pragma unroll
    for (int ddt = 0; ddt < 16; ddt++){
      int dd = ddt * 16 + l15;
      int g2 = l4 ^ (dd & 3) ^ ((dd >> 2) & 3);
      bf16x8 wf2 = *(const bf16x8*)(w2b + dd * 64 + g2 * 16);
      oacc[ddt][0] = __builtin_amdgcn_mfma_f32_16x16x32_bf16(wf2, aa[0], oacc[ddt][0], 0, 0, 0);
      oacc[ddt][1] = __builtin_amdgcn_mfma_f32_16x16x32_bf16(wf2, aa[1], oacc[ddt][1], 0, 0, 0);
    }
    __builtin_amdgcn_s_setprio(0);

    // ---- write prefetched weights into the other buffers
    if (pf){
      char* w1n = lds_all + (cur ^ 1) * 16384;
      char* w2n = lds_all + 32768 + (cur ^ 1) * 16384;
      *(uint4*)(w1n + dA0) = va0;
      *(uint4*)(w1n + dA1) = va1;
      *(uint4*)(w2n + dB0) = vb0;
      *(uint4*)(w2n + dB1) = vb1;
    }
    __syncthreads();
  }

  // ---- epilogue: per-wave 8KB LDS slice, transpose to coalesced 512B row stores
  char* slice = lds_all + w * 8192;
  const int gsl = l & 31;          // granule 0..31 (4 f32 = 4 dd)
  const int rhalf = l >> 5;        // 0..1
  #pragma unroll
  for (int nset = 0; nset < 2; nset++){
    #pragma unroll
    for (int half = 0; half < 2; half++){
      #pragma unroll
      for (int dq = 0; dq < 8; dq++){
        int ddt = half * 8 + dq;
        *(f32x4*)(slice + l15 * 512 + (((dq * 4 + l4) ^ (l15 & 7)) * 16)) = oacc[ddt][nset];
      }
      float4 b2v = *(const float4*)(b2 + (size_t)h * 256 + half * 128 + gsl * 4);
      #pragma unroll
      for (int j = 0; j < 8; j++){
        int rr = rhalf + j * 2;
        f32x4 v = *(const f32x4*)(slice + rr * 512 + ((gsl ^ (rr & 7)) * 16));
        int n = nw + nset * 16 + rr;
        if (n < N_NODES){
          float4 o;
          o.x = v[0] + b2v.x; o.y = v[1] + b2v.y;
          o.z = v[2] + b2v.z; o.w = v[3] + b2v.w;
          *(float4*)(out + (size_t)n * (HEADS * HID) + h * HID + half * 128 + gsl * 4) = o;
        }
      }
    }
  }
}

extern "C" void kernel_launch(void* const* d_in, const int* in_sizes, int n_in,
                              void* d_out, int out_size, void* d_ws, size_t ws_size,
                              hipStream_t stream){
  const float* x     = (const float*)d_in[0];
  const int*   ei    = (const int*)  d_in[1];
  const float* Wb    = (const float*)d_in[2];
  const float* bb    = (const float*)d_in[3];
  const float* W1    = (const float*)d_in[4];
  const float* b1    = (const float*)d_in[5];
  const float* gamma = (const float*)d_in[6];
  const float* beta  = (const float*)d_in[7];
  const float* W2    = (const float*)d_in[8];
  const float* b2    = (const float*)d_in[9];
  float* out = (float*)d_out;

  char* ws = (char*)d_ws;
  size_t off = 0;
  auto alloc = [&](size_t bytes){ void* p = ws + off; off += (bytes + 255) & ~(size_t)255; return p; };
  float*    agg  = (float*)   alloc((size_t)N_NODES * IN_DIM * 4);
  ushort_t* hbf  = (ushort_t*)alloc((size_t)N_NODES * HID * 2);
  ushort_t* w1t  = (ushort_t*)alloc((size_t)HEADS * MAXW * HID * 2);
  ushort_t* w2t  = (ushort_t*)alloc((size_t)HEADS * HID * MAXW * 2);
  float*    G    = (float*)   alloc(256 * 256 * 4);
  float*    s    = (float*)   alloc(256 * 4);
  float*    As   = (float*)   alloc((size_t)HEADS * MAXW * 4);
  float*    Bs   = (float*)   alloc((size_t)HEADS * MAXW * 4);
  int*      flg  = (int*)     alloc(256);
  int*      deg  = (int*)     alloc((size_t)N_NODES * 4);
  int*      st   = (int*)     alloc((size_t)N_NODES * 4);
  int*      cur  = (int*)     alloc((size_t)N_NODES * 4);
  int*      eids = (int*)     alloc((size_t)E_EDGES * 4);

  hipLaunchKernelGGL(k_init,      dim3(512),         dim3(256), 0, stream, G, s, deg);
  hipLaunchKernelGGL(k_detect,    dim3(1),           dim3(256), 0, stream, ei, flg);
  hipLaunchKernelGGL(k_transpose, dim3(128, 32, 2),  dim3(256), 0, stream, W1, W2, w1t, w2t);
  hipLaunchKernelGGL(k_hist,      dim3(2500),        dim3(256), 0, stream, ei, flg, deg);
  hipLaunchKernelGGL(k_scan,      dim3(1),           dim3(256), 0, stream, deg, st, cur);
  hipLaunchKernelGGL(k_scatter,   dim3(2500),        dim3(256), 0, stream, ei, flg, cur, eids);
  hipLaunchKernelGGL(k_agg,       dim3(5000),        dim3(256), 0, stream, x, st, deg, eids, agg);
  hipLaunchKernelGGL(k_backbone,  dim3(625),         dim3(256), 0, stream, agg, Wb, bb, hbf, s);
  hipLaunchKernelGGL(k_gram,      dim3(16, 25),      dim3(256), 0, stream, hbf, G);
  hipLaunchKernelGGL(k_stats,     dim3(8, 32),       dim3(256), 0, stream, G, s, w1t, b1, gamma, beta, As, Bs);
  hipLaunchKernelGGL(k_main,      dim3(79, 32),      dim3(512), 0, stream, hbf, w1t, w2t, As, Bs, b2, out);
}